// Round 6
// baseline (173.303 us; speedup 1.0000x reference)
//
#include <hip/hip_runtime.h>
#include <hip/hip_bf16.h>
#include <math.h>

// Shapes (hard-coded by the problem)
#define B_   128
#define C1_  128
#define C2_  14
#define S_   14
#define K_   3
#define H_   256
#define E_   2

// Robust scalar decode: int32/int64/float32/float64 bit patterns.
// Ordered so a plain int32 never reads past its 4 bytes.
__device__ __forceinline__ int decode_shift(const int* p) {
    int a = p[0];
    if (a >= -100 && a <= 100 && a != 0) return a;             // int32/int64 low word
    float f = __int_as_float(a);                                // float32?
    if (f >= -100.f && f <= 100.f && f == truncf(f) && f != 0.f) return (int)f;
    long long bits = ((long long)p[1] << 32) | (unsigned int)a; // float64?
    double d = __longlong_as_double(bits);
    if (d >= -100.0 && d <= 100.0 && d == trunc(d) && d != 0.0) return (int)d;
    return a;  // genuine 0
}

// Kernel A: t4[b,h,c2,s] = sum_{c1,k} x[b,c1,c2,s+k-1] * w1[c1,k,h]
// (zero-padded in s). All fp32. t4 staged INTO d_out (identical element count).
__global__ __launch_bounds__(256) void t4_kernel(const float* __restrict__ x,
                                                 const float* __restrict__ w1,
                                                 float* __restrict__ t4) {
    __shared__ float xl[C1_][16];   // xl[c1][p] = x[b,c1,c2,p-1], zero-padded p=0,15
    const int b  = blockIdx.x / C2_;
    const int c2 = blockIdx.x % C2_;
    const int h  = threadIdx.x;

    for (int i = h; i < C1_ * S_; i += 256) {
        int c1 = i / S_, s = i % S_;
        xl[c1][s + 1] = x[((size_t)(b * C1_ + c1) * C2_ + c2) * S_ + s];
    }
    if (h < C1_) { xl[h][0] = 0.f; xl[h][15] = 0.f; }
    __syncthreads();

    float acc[S_];
#pragma unroll
    for (int s = 0; s < S_; ++s) acc[s] = 0.f;

    for (int c1 = 0; c1 < C1_; ++c1) {
        float wa = w1[(size_t)(c1 * K_ + 0) * H_ + h];
        float wb = w1[(size_t)(c1 * K_ + 1) * H_ + h];
        float wc = w1[(size_t)(c1 * K_ + 2) * H_ + h];
        float xv[16];
#pragma unroll
        for (int p = 0; p < 16; ++p) xv[p] = xl[c1][p];
#pragma unroll
        for (int s = 0; s < S_; ++s)
            acc[s] += wa * xv[s] + wb * xv[s + 1] + wc * xv[s + 2];
    }

    size_t base = ((size_t)(b * H_ + h) * C2_ + c2) * S_;
#pragma unroll
    for (int s = 0; s < S_; ++s) t4[base + s] = acc[s];
}

// Kernel B: IN-PLACE on d_out (fp32). Each thread owns column (b,h,:,m): reads
// its own 14 t4 values, applies the collapsed double-roll two-tap combine
//   out[b,h,n,m] = sum_e w0[h,ep] * t4[b,h,c2p,m],
//   q=(2n+e-shift)%28, np=q>>1, ep=q&1, c2p=(np-shift)%14
// and writes back the same 14 locations. No cross-thread overlap -> race-free.
#define HT_ 16                      // h-tile per block; block = HT_*S_ = 224 threads
__global__ __launch_bounds__(HT_ * S_) void out_kernel(float* __restrict__ t4,
                                                       const float* __restrict__ w0,
                                                       const int* __restrict__ shift_p) {
    const int tid = threadIdx.x;
    const int m  = tid % S_;
    const int hh = tid / S_;                    // 0..HT_-1
    const int b  = blockIdx.x / (H_ / HT_);
    const int h  = (blockIdx.x % (H_ / HT_)) * HT_ + hh;
    const int shift = decode_shift(shift_p);

    const size_t colbase = ((size_t)(b * H_ + h) * C2_) * S_ + m;  // [b][h][0][m]
    float tl[C2_];
#pragma unroll
    for (int c2 = 0; c2 < C2_; ++c2)
        tl[c2] = t4[colbase + (size_t)c2 * S_];

    const float w0v[2] = { w0[h * E_ + 0], w0[h * E_ + 1] };

    float r[C2_];
#pragma unroll
    for (int n = 0; n < C2_; ++n) {
        float acc = 0.f;
#pragma unroll
        for (int e = 0; e < E_; ++e) {
            int q = (2 * n + e - shift) % (C2_ * E_); if (q < 0) q += C2_ * E_;
            int np = q >> 1, ep = q & 1;
            int c2 = (np - shift) % C2_; if (c2 < 0) c2 += C2_;
            acc += tl[c2] * w0v[ep];
        }
        r[n] = acc;
    }
#pragma unroll
    for (int n = 0; n < C2_; ++n)
        t4[colbase + (size_t)n * S_] = r[n];
}

extern "C" void kernel_launch(void* const* d_in, const int* in_sizes, int n_in,
                              void* d_out, int out_size, void* d_ws, size_t ws_size,
                              hipStream_t stream) {
    // Size-based input resolution (sizes unique); positional fallback.
    const float* x     = (const float*)d_in[0];
    const float* w0    = (const float*)d_in[1];
    const float* w1    = (const float*)d_in[2];
    const int*   shift = (const int*)(n_in > 3 ? d_in[3] : d_in[n_in - 1]);
    for (int i = 0; i < n_in; ++i) {
        int sz = in_sizes[i];
        if (sz == B_ * C1_ * C2_ * S_)      x     = (const float*)d_in[i];
        else if (sz == H_ * E_)             w0    = (const float*)d_in[i];
        else if (sz == C1_ * K_ * H_)       w1    = (const float*)d_in[i];
        else if (sz == 1)                   shift = (const int*)d_in[i];
    }
    float* out = (float*)d_out;  // fp32 output; doubles as t4 staging

    t4_kernel<<<B_ * C2_, 256, 0, stream>>>(x, w1, out);
    out_kernel<<<B_ * (H_ / HT_), HT_ * S_, 0, stream>>>(out, w0, shift);
}

// Round 7
// 109.210 us; speedup vs baseline: 1.5869x; 1.5869x over previous
//
#include <hip/hip_runtime.h>
#include <hip/hip_bf16.h>
#include <math.h>

// Shapes (hard-coded by the problem)
#define B_   128
#define C1_  128
#define C2_  14
#define S_   14
#define K_   3
#define H_   256
#define E_   2

#define HT   64          // h-tile per block -> grid = 128 b * 4 = 512 blocks (2/CU)
#define NT   4           // 4 n-subtiles of 16 per block
#define MT   13          // m-tiles of 16 (208 rows >= 196 real)
#define CH   64          // c1 half staged per K-phase
#define XSTR 72          // xT inner stride (64 c1 + pad): row 144 B, 16B-aligned
#define BSTR 200         // Bt inner stride (192 kappa + pad): row 400 B, 16B-aligned
#define CSTR 68          // C_lds inner stride (64 h + pad)

typedef __attribute__((ext_vector_type(8))) short bf16x8;
typedef __attribute__((ext_vector_type(4))) float f32x4;

__device__ __forceinline__ unsigned short f2bf(float f) {  // RNE fp32->bf16
    unsigned int u = __float_as_uint(f);
    return (unsigned short)((u + 0x7FFF + ((u >> 16) & 1)) >> 16);
}

// Robust scalar decode (int32/int64/float32/float64 bit patterns).
__device__ __forceinline__ int decode_shift(const int* p) {
    int a = p[0];
    if (a >= -100 && a <= 100 && a != 0) return a;
    float f = __int_as_float(a);
    if (f >= -100.f && f <= 100.f && f == truncf(f) && f != 0.f) return (int)f;
    long long bits = ((long long)p[1] << 32) | (unsigned int)a;
    double d = __longlong_as_double(bits);
    if (d >= -100.0 && d <= 100.0 && d == trunc(d) && d != 0.0) return (int)d;
    return a;
}

// Fused: GEMM t4[(b,c2,s),(h)] = sum_{kk,c1} x[b,c1,c2,s+kk-1] * w1[c1,kk,h]
// via 16x16x32 bf16 MFMA, + in-LDS collapsed double-roll epilogue:
//   out[b,h,n,m] = sum_e w0[h,ep] * t4[b,c2p,m,h],
//   q=(2n+e-shift)%28, np=q>>1, ep=q&1, c2p=(np-shift)%14   (verified R6)
__global__ __launch_bounds__(256, 2) void fused_kernel(const float* __restrict__ x,
                                                       const float* __restrict__ w0,
                                                       const float* __restrict__ w1,
                                                       const int* __restrict__ shift_p,
                                                       float* __restrict__ out) {
    __shared__ __align__(16) char lds[60160];
    unsigned short* xT = (unsigned short*)lds;            // [15][16][XSTR] bf16 (c2=14 slice: garbage pad rows)
    unsigned short* Bt = (unsigned short*)(lds + 34560);  // [HT][BSTR]     bf16
    float*          Cl = (float*)lds;                     // [208][CSTR]    fp32 (reused after K-loop)

    const int b    = blockIdx.x >> 2;
    const int h0   = (blockIdx.x & 3) * HT;
    const int t    = threadIdx.x;
    const int wave = t >> 6;
    const int lane = t & 63;
    const int quad = lane >> 4;
    const int l15  = lane & 15;

    f32x4 acc[4][NT];
#pragma unroll
    for (int i = 0; i < 4; ++i)
#pragma unroll
        for (int j = 0; j < NT; ++j) acc[i][j] = (f32x4){0.f, 0.f, 0.f, 0.f};

    for (int hf = 0; hf < 2; ++hf) {
        if (hf) __syncthreads();
        // ---- stage xT[c2][s+1][c1l] = bf16(x[b][hf*CH+c1l][c2][s]); coalesced global reads
        const float* xb = x + ((size_t)b * C1_ + hf * CH) * (C2_ * S_);
        for (int idx = t; idx < CH * 196; idx += 256) {
            int c1l = idx / 196, cs = idx - c1l * 196;
            int c2 = cs / S_, s = cs - c2 * S_;
            xT[(c2 * 16 + s + 1) * XSTR + c1l] = f2bf(xb[c1l * 196 + cs]);
        }
        // zero conv pads p=0,15
        for (int idx = t; idx < C2_ * CH * 2; idx += 256) {
            int c2 = idx / (CH * 2), r = idx - c2 * CH * 2;
            int p = (r < CH) ? 0 : 15, c1l = (r < CH) ? r : r - CH;
            xT[(c2 * 16 + p) * XSTR + c1l] = 0;
        }
        // ---- stage Bt[hl][kk*CH+c1l] = bf16(w1[hf*CH+c1l][kk][h0+hl]); coalesced in hl
        for (int idx = t; idx < CH * K_ * HT; idx += 256) {
            int hl = idx & (HT - 1);
            int rest = idx >> 6;                 // [0, 192)
            int kk = rest / CH, c1l = rest - kk * CH;
            Bt[hl * BSTR + kk * CH + c1l] =
                f2bf(w1[((size_t)(hf * CH + c1l) * K_ + kk) * H_ + h0 + hl]);
        }
        __syncthreads();

        // ---- K-phase: 6 MFMA steps of 32 (kk = tt>>1, c1-block = (tt&1)*32)
#pragma unroll
        for (int tt = 0; tt < 6; ++tt) {
            const int kk = tt >> 1;
            const int c1off = (tt & 1) * 32 + quad * 8;
            bf16x8 bf[NT];
#pragma unroll
            for (int nc = 0; nc < NT; ++nc)
                bf[nc] = *(const bf16x8*)&Bt[(nc * 16 + l15) * BSTR + tt * 32 + quad * 8];
#pragma unroll
            for (int mi = 0; mi < 4; ++mi) {
                int mt = wave + mi * 4;          // wave-interleaved m-tiles
                if (mt < MT) {
                    int r = mt * 16 + l15;
                    int c2 = r / 14, s = r - c2 * 14;
                    bf16x8 af = *(const bf16x8*)&xT[(c2 * 16 + s + kk) * XSTR + c1off];
#pragma unroll
                    for (int nc = 0; nc < NT; ++nc)
                        acc[mi][nc] = __builtin_amdgcn_mfma_f32_16x16x32_bf16(
                            af, bf[nc], acc[mi][nc], 0, 0, 0);
                }
            }
        }
    }

    __syncthreads();
    // ---- C -> LDS (C/D layout: row = quad*4+reg, col = l15)
#pragma unroll
    for (int mi = 0; mi < 4; ++mi) {
        int mt = wave + mi * 4;
        if (mt < MT) {
#pragma unroll
            for (int nc = 0; nc < NT; ++nc) {
                int hl = nc * 16 + l15;
#pragma unroll
                for (int reg = 0; reg < 4; ++reg)
                    Cl[(mt * 16 + quad * 4 + reg) * CSTR + hl] = acc[mi][nc][reg];
            }
        }
    }
    __syncthreads();

    // ---- epilogue: rolled 2-tap combine, coalesced fp32 stores
    const int shift = decode_shift(shift_p);
    for (int idx = t; idx < HT * 196; idx += 256) {
        int hl = idx / 196, nm = idx - hl * 196;
        int n = nm / S_, m = nm - n * S_;
        int h = h0 + hl;
        float v = 0.f;
#pragma unroll
        for (int e = 0; e < E_; ++e) {
            int q = (2 * n + e - shift) % (C2_ * E_); if (q < 0) q += C2_ * E_;
            int np = q >> 1, ep = q & 1;
            int c2 = (np - shift) % C2_; if (c2 < 0) c2 += C2_;
            v += w0[h * E_ + ep] * Cl[(c2 * S_ + m) * CSTR + hl];
        }
        out[((size_t)(b * H_ + h) * C2_ + n) * S_ + m] = v;
    }
}

extern "C" void kernel_launch(void* const* d_in, const int* in_sizes, int n_in,
                              void* d_out, int out_size, void* d_ws, size_t ws_size,
                              hipStream_t stream) {
    const float* x     = (const float*)d_in[0];
    const float* w0    = (const float*)d_in[1];
    const float* w1    = (const float*)d_in[2];
    const int*   shift = (const int*)(n_in > 3 ? d_in[3] : d_in[n_in - 1]);
    for (int i = 0; i < n_in; ++i) {
        int sz = in_sizes[i];
        if (sz == B_ * C1_ * C2_ * S_)      x     = (const float*)d_in[i];
        else if (sz == H_ * E_)             w0    = (const float*)d_in[i];
        else if (sz == C1_ * K_ * H_)       w1    = (const float*)d_in[i];
        else if (sz == 1)                   shift = (const int*)d_in[i];
    }
    float* out = (float*)d_out;

    fused_kernel<<<B_ * (H_ / HT), 256, 0, stream>>>(x, w0, w1, shift, out);
}

// Round 8
// 93.437 us; speedup vs baseline: 1.8548x; 1.1688x over previous
//
#include <hip/hip_runtime.h>
#include <hip/hip_bf16.h>
#include <math.h>

// Shapes (hard-coded by the problem)
#define B_   128
#define C1_  128
#define C2_  14
#define S_   14
#define K_   3
#define H_   256
#define E_   2

#define HT   64          // h-tile per block -> grid = 128 b * 4 = 512 blocks (2/CU)
#define NT   4           // n-subtiles of 16
#define MT   13          // m-tiles of 16 (208 rows >= 196 real)
#define CH   64          // c1 half per K-phase
#define XSTR 72          // xT inner stride (u16): row = 144 B (16B aligned)
#define BSTR 200         // Bt inner stride (u16): row = 400 B (16B aligned)
#define CROW 212         // Cl inner stride (f32): row = 848 B (16B aligned)

typedef unsigned short u16;
typedef unsigned int   u32;
typedef __attribute__((ext_vector_type(8))) short bf16x8;
typedef __attribute__((ext_vector_type(4))) float f32x4;

__device__ __forceinline__ u16 f2bf(float f) {  // RNE fp32->bf16
    u32 u = __float_as_uint(f);
    return (u16)((u + 0x7FFF + ((u >> 16) & 1)) >> 16);
}

__device__ __forceinline__ int decode_shift(const int* p) {
    int a = p[0];
    if (a >= -100 && a <= 100 && a != 0) return a;
    float f = __int_as_float(a);
    if (f >= -100.f && f <= 100.f && f == truncf(f) && f != 0.f) return (int)f;
    long long bits = ((long long)p[1] << 32) | (unsigned int)a;
    double d = __longlong_as_double(bits);
    if (d >= -100.0 && d <= 100.0 && d == trunc(d) && d != 0.0) return (int)d;
    return a;
}

// Pre-convert: x (3,211,264 f32) and w1 (98,304 f32) -> bf16 in d_ws.
__global__ __launch_bounds__(256) void cvt_kernel(const float* __restrict__ x,
                                                  const float* __restrict__ w1,
                                                  u16* __restrict__ xb,
                                                  u16* __restrict__ w1b) {
    const int NXq = (B_ * C1_ * C2_ * S_) / 4;   // 802,816
    const int NWq = (C1_ * K_ * H_) / 4;         // 24,576
    int q = blockIdx.x * 256 + threadIdx.x;
    float4 v; u16* dst;
    if (q < NXq)      { v = ((const float4*)x)[q];        dst = xb  + (size_t)q * 4; }
    else { int r = q - NXq; if (r >= NWq) return;
                       v = ((const float4*)w1)[r];        dst = w1b + (size_t)r * 4; }
    u32 lo = (u32)f2bf(v.x) | ((u32)f2bf(v.y) << 16);
    u32 hi = (u32)f2bf(v.z) | ((u32)f2bf(v.w) << 16);
    *(uint2*)dst = make_uint2(lo, hi);
}

// Fused GEMM (16x16x32 bf16 MFMA) + in-LDS double-roll epilogue (math identical
// to R7, which passed). PRE: sources already bf16 in d_ws.
template <bool PRE>
__global__ __launch_bounds__(256, 2) void fused_kernel(const void* __restrict__ xsrc,
                                                       const float* __restrict__ w0,
                                                       const void* __restrict__ wsrc,
                                                       const int* __restrict__ shift_p,
                                                       float* __restrict__ out) {
    __shared__ __align__(16) char lds[60160];
    u16*   xT = (u16*)lds;             // [15*16 rows][XSTR]
    u16*   Bt = (u16*)(lds + 34560);   // [HT][BSTR]
    float* Cl = (float*)lds;           // [HT][CROW] fp32, reused after K-loop

    const int b    = blockIdx.x >> 2;
    const int h0   = (blockIdx.x & 3) * HT;
    const int t    = threadIdx.x;
    const int wave = t >> 6;
    const int lane = t & 63;
    const int quad = lane >> 4;
    const int l15  = lane & 15;

    f32x4 acc[4][NT];
#pragma unroll
    for (int i = 0; i < 4; ++i)
#pragma unroll
        for (int j = 0; j < NT; ++j) acc[i][j] = (f32x4){0.f, 0.f, 0.f, 0.f};

    for (int hf = 0; hf < 2; ++hf) {
        if (hf) __syncthreads();
        // ---- x stage: task (oct, cs); 8 c1-strided loads (wave-coalesced in cs),
        //      pack, one b128 row-contiguous LDS write (conflict-free).
        {
            const int oct = t >> 5, cs0 = t & 31;
            const int c1b = hf * CH + oct * 8;
#pragma unroll
            for (int i = 0; i < 7; ++i) {
                int cs = cs0 + 32 * i;
                if (cs < 196) {
                    int c2 = cs / 14, s = cs - c2 * 14;
                    u16 v[8];
                    if (PRE) {
                        const u16* xbp = (const u16*)xsrc + (size_t)b * (C1_ * 196);
#pragma unroll
                        for (int j = 0; j < 8; ++j) v[j] = xbp[(c1b + j) * 196 + cs];
                    } else {
                        const float* xf = (const float*)xsrc + (size_t)b * (C1_ * 196);
#pragma unroll
                        for (int j = 0; j < 8; ++j) v[j] = f2bf(xf[(c1b + j) * 196 + cs]);
                    }
                    u32 w[4];
#pragma unroll
                    for (int j = 0; j < 4; ++j) w[j] = (u32)v[2 * j] | ((u32)v[2 * j + 1] << 16);
                    *(uint4*)&xT[(c2 * 16 + s + 1) * XSTR + oct * 8] = make_uint4(w[0], w[1], w[2], w[3]);
                }
            }
            if (t < 224) {  // zero conv pads p=0,15 (14 c2 x 2 p x 8 octs)
                int c2 = t >> 4, r = t & 15;
                int p = (r & 1) ? 15 : 0, o = r >> 1;
                *(uint4*)&xT[(c2 * 16 + p) * XSTR + o * 8] = make_uint4(0, 0, 0, 0);
            }
        }
        // ---- Bt stage: task (kappa-oct, hl); loads wave-coalesced in hl; b128 writes.
        {
            const int hl = t & 63, oc0 = t >> 6;
#pragma unroll
            for (int i = 0; i < 6; ++i) {
                int oc = oc0 + 4 * i;
                int kk = oc >> 3, o8 = (oc & 7) * 8;
                u16 v[8];
                if (PRE) {
                    const u16* wb = (const u16*)wsrc;
#pragma unroll
                    for (int j = 0; j < 8; ++j)
                        v[j] = wb[((hf * CH + o8 + j) * 3 + kk) * H_ + h0 + hl];
                } else {
                    const float* wf = (const float*)wsrc;
#pragma unroll
                    for (int j = 0; j < 8; ++j)
                        v[j] = f2bf(wf[((hf * CH + o8 + j) * 3 + kk) * H_ + h0 + hl]);
                }
                u32 w[4];
#pragma unroll
                for (int j = 0; j < 4; ++j) w[j] = (u32)v[2 * j] | ((u32)v[2 * j + 1] << 16);
                *(uint4*)&Bt[hl * BSTR + kk * 64 + o8] = make_uint4(w[0], w[1], w[2], w[3]);
            }
        }
        __syncthreads();

        // ---- K-phase: 6 MFMA steps of 32 (kk = tt>>1, c1-block = (tt&1)*32)
#pragma unroll
        for (int tt = 0; tt < 6; ++tt) {
            const int kk = tt >> 1;
            const int c1off = (tt & 1) * 32 + quad * 8;
            bf16x8 bf[NT];
#pragma unroll
            for (int nc = 0; nc < NT; ++nc)
                bf[nc] = *(const bf16x8*)&Bt[(nc * 16 + l15) * BSTR + tt * 32 + quad * 8];
#pragma unroll
            for (int mi = 0; mi < 4; ++mi) {
                int mt = wave + mi * 4;
                if (mt < MT) {
                    int r = mt * 16 + l15;
                    int c2 = r / 14, s = r - c2 * 14;
                    bf16x8 af = *(const bf16x8*)&xT[(c2 * 16 + s + kk) * XSTR + c1off];
#pragma unroll
                    for (int nc = 0; nc < NT; ++nc)
                        acc[mi][nc] = __builtin_amdgcn_mfma_f32_16x16x32_bf16(
                            af, bf[nc], acc[mi][nc], 0, 0, 0);
                }
            }
        }
    }

    __syncthreads();
    // ---- C -> LDS transposed: Cl[hl][row]; f32x4 stores (reg dim contiguous)
#pragma unroll
    for (int mi = 0; mi < 4; ++mi) {
        int mt = wave + mi * 4;
        if (mt < MT) {
#pragma unroll
            for (int nc = 0; nc < NT; ++nc) {
                int hl = nc * 16 + l15;
                *(f32x4*)&Cl[hl * CROW + mt * 16 + quad * 4] = acc[mi][nc];
            }
        }
    }
    __syncthreads();

    // ---- epilogue: 2-tap roll combine. Thread owns fixed hl; taps' ep/weight
    //      are n-independent (parity of q=(2n+e-shift)%28 invariant in n).
    const int shift = decode_shift(shift_p);
    const int hl = t >> 2, sub = t & 3;
    const int h = h0 + hl;
    int   c0[2]; float wv[2];
#pragma unroll
    for (int e = 0; e < 2; ++e) {
        int q = (e - shift) % 28; if (q < 0) q += 28;
        int np0 = q >> 1, ep = q & 1;
        int c = (np0 - shift) % 14; if (c < 0) c += 14;
        c0[e] = c;
        wv[e] = w0[h * 2 + ep];
    }
    const float* Crow = &Cl[hl * CROW];
    float* orow = out + (size_t)(b * H_ + h) * 196;
    int m = sub, n = 0;
    for (int i = 0; i < 49; ++i) {
        int cA = c0[0] + n; if (cA >= 14) cA -= 14;
        int cB = c0[1] + n; if (cB >= 14) cB -= 14;
        orow[n * 14 + m] = wv[0] * Crow[cA * 14 + m] + wv[1] * Crow[cB * 14 + m];
        m += 4; if (m >= 14) { m -= 14; ++n; }
    }
}

extern "C" void kernel_launch(void* const* d_in, const int* in_sizes, int n_in,
                              void* d_out, int out_size, void* d_ws, size_t ws_size,
                              hipStream_t stream) {
    const float* x     = (const float*)d_in[0];
    const float* w0    = (const float*)d_in[1];
    const float* w1    = (const float*)d_in[2];
    const int*   shift = (const int*)(n_in > 3 ? d_in[3] : d_in[n_in - 1]);
    for (int i = 0; i < n_in; ++i) {
        int sz = in_sizes[i];
        if (sz == B_ * C1_ * C2_ * S_)      x     = (const float*)d_in[i];
        else if (sz == H_ * E_)             w0    = (const float*)d_in[i];
        else if (sz == C1_ * K_ * H_)       w1    = (const float*)d_in[i];
        else if (sz == 1)                   shift = (const int*)d_in[i];
    }
    float* out = (float*)d_out;

    const size_t NX = (size_t)B_ * C1_ * C2_ * S_;   // 3,211,264
    const size_t NW = (size_t)C1_ * K_ * H_;         // 98,304
    if (ws_size >= (NX + NW) * sizeof(u16)) {
        u16* xb  = (u16*)d_ws;
        u16* w1b = xb + NX;
        const int NQ = (int)((NX + NW) / 4);         // 827,392 = 3232*256
        cvt_kernel<<<(NQ + 255) / 256, 256, 0, stream>>>(x, w1, xb, w1b);
        fused_kernel<true><<<B_ * (H_ / HT), 256, 0, stream>>>(xb, w0, w1b, shift, out);
    } else {
        fused_kernel<false><<<B_ * (H_ / HT), 256, 0, stream>>>(x, w0, w1, shift, out);
    }
}